// Round 1
// baseline (293.061 us; speedup 1.0000x reference)
//
#include <hip/hip_runtime.h>

// out[r, i] = sum_{k=0..4} W[i,k] * x[r, i+k-2] + b[i], zero-padded at edges.
// B=8192 rows, C=4096 channels, K=5. Pure fp32, memory-bound streaming stencil.
// One thread = 4 consecutive channels (float4). Window x[c-2..c+5] covered by
// 3 aligned float4 loads; edge chunks substituted with zero (== zero padding).

#define B_ROWS 8192
#define C_CH   4096
#define KWIN   5

__global__ __launch_bounds__(256) void grouped_linear_kernel(
    const float* __restrict__ x, const float* __restrict__ W,
    const float* __restrict__ bias, float* __restrict__ out)
{
    const int tid = blockIdx.x * blockDim.x + threadIdx.x;
    const int r  = tid >> 10;          // C/4 = 1024 chunks per row
    const int ci = tid & 1023;         // chunk index within row
    const int c  = ci << 2;            // base channel (multiple of 4)

    const float4* xv = (const float4*)(x + (size_t)r * C_CH);
    const float4 zero = make_float4(0.f, 0.f, 0.f, 0.f);

    // Aligned loads covering x[c-4 .. c+7]; we use x[c-2 .. c+5].
    const float4 xm = (c > 0)          ? xv[ci - 1] : zero;
    const float4 xc = xv[ci];
    const float4 xp = (c + 4 < C_CH)   ? xv[ci + 1] : zero;

    // win[m] = x[r, c - 2 + m], m = 0..7
    const float win0 = xm.z, win1 = xm.w;
    const float win2 = xc.x, win3 = xc.y, win4 = xc.z, win5 = xc.w;
    const float win6 = xp.x, win7 = xp.y;

    // W rows c..c+3: 20 contiguous floats, (c*5) % 4 == 0 so aligned float4s.
    const float4* W4 = (const float4*)(W + (size_t)c * KWIN);
    const float4 w0 = W4[0];  // W[c][0..3]
    const float4 w1 = W4[1];  // W[c][4], W[c+1][0..2]
    const float4 w2 = W4[2];  // W[c+1][3..4], W[c+2][0..1]
    const float4 w3 = W4[3];  // W[c+2][2..4], W[c+3][0]
    const float4 w4 = W4[4];  // W[c+3][1..4]

    const float4 bv = ((const float4*)bias)[ci];

    // out[c+j] = sum_{k} W[c+j][k] * win[j+k] + bias[c+j]
    float4 o;
    o.x = fmaf(w0.x, win0, fmaf(w0.y, win1, fmaf(w0.z, win2, fmaf(w0.w, win3, fmaf(w1.x, win4, bv.x)))));
    o.y = fmaf(w1.y, win1, fmaf(w1.z, win2, fmaf(w1.w, win3, fmaf(w2.x, win4, fmaf(w2.y, win5, bv.y)))));
    o.z = fmaf(w2.z, win2, fmaf(w2.w, win3, fmaf(w3.x, win4, fmaf(w3.y, win5, fmaf(w3.z, win6, bv.z)))));
    o.w = fmaf(w3.w, win3, fmaf(w4.x, win4, fmaf(w4.y, win5, fmaf(w4.z, win6, fmaf(w4.w, win7, bv.w)))));

    ((float4*)(out + (size_t)r * C_CH))[ci] = o;
}

extern "C" void kernel_launch(void* const* d_in, const int* in_sizes, int n_in,
                              void* d_out, int out_size, void* d_ws, size_t ws_size,
                              hipStream_t stream) {
    const float* x    = (const float*)d_in[0];
    const float* W    = (const float*)d_in[1];
    const float* bias = (const float*)d_in[2];
    float* out = (float*)d_out;

    const int total_threads = (B_ROWS * C_CH) / 4;   // 8,388,608
    const int block = 256;
    const int grid  = total_threads / block;         // 32,768

    grouped_linear_kernel<<<grid, block, 0, stream>>>(x, W, bias, out);
}

// Round 2
// 250.624 us; speedup vs baseline: 1.1693x; 1.1693x over previous
//
#include <hip/hip_runtime.h>

// out[r, i] = sum_{k=0..4} W[i,k] * x[r, i+k-2] + b[i], zero-padded at edges.
// B=8192 rows, C=4096 channels, K=5, fp32.
//
// R1 lesson: per-(row,channel) W loads (80 B lane stride) made the kernel
// L1/TA line-request bound (~400 line-req/wave for W alone -> 136 us @ 1.5 TB/s).
// R2: each thread owns 4 fixed channels, loads W (5xfloat4) + bias (float4)
// into registers ONCE, then loops over ROWS_PER_BLOCK rows. Per-row VMEM is
// 3 coalesced float4 x-loads + 1 float4 store.

#define B_ROWS 8192
#define C_CH   4096
#define KWIN   5
#define ROWS_PER_BLOCK 16

__global__ __launch_bounds__(256) void grouped_linear_kernel(
    const float* __restrict__ x, const float* __restrict__ W,
    const float* __restrict__ bias, float* __restrict__ out)
{
    // chunk = which group of 4 channels this thread owns (0..1023)
    const int chunk = (blockIdx.x << 8) + threadIdx.x;   // gridDim.x == 4
    const int c     = chunk << 2;                        // base channel
    const int r0    = blockIdx.y * ROWS_PER_BLOCK;

    // --- loop-invariant: W rows c..c+3 (20 contiguous floats) + bias ---
    const float4* W4 = (const float4*)(W + (size_t)c * KWIN);
    const float4 w0 = W4[0];  // W[c][0..3]
    const float4 w1 = W4[1];  // W[c][4], W[c+1][0..2]
    const float4 w2 = W4[2];  // W[c+1][3..4], W[c+2][0..1]
    const float4 w3 = W4[3];  // W[c+2][2..4], W[c+3][0]
    const float4 w4 = W4[4];  // W[c+3][1..4]
    const float4 bv = ((const float4*)bias)[chunk];

    const bool has_m = (c > 0);
    const bool has_p = (c + 4 < C_CH);
    const float4 zero = make_float4(0.f, 0.f, 0.f, 0.f);

    const float4* xrow = (const float4*)(x   + (size_t)r0 * C_CH);
    float4*       orow = (float4*)      (out + (size_t)r0 * C_CH);

    #pragma unroll 2
    for (int r = 0; r < ROWS_PER_BLOCK; ++r) {
        const float4 xm = has_m ? xrow[chunk - 1] : zero;
        const float4 xc = xrow[chunk];
        const float4 xp = has_p ? xrow[chunk + 1] : zero;

        // win[m] = x[r, c - 2 + m], m = 0..7
        const float win0 = xm.z, win1 = xm.w;
        const float win2 = xc.x, win3 = xc.y, win4 = xc.z, win5 = xc.w;
        const float win6 = xp.x, win7 = xp.y;

        float4 o;
        o.x = fmaf(w0.x, win0, fmaf(w0.y, win1, fmaf(w0.z, win2, fmaf(w0.w, win3, fmaf(w1.x, win4, bv.x)))));
        o.y = fmaf(w1.y, win1, fmaf(w1.z, win2, fmaf(w1.w, win3, fmaf(w2.x, win4, fmaf(w2.y, win5, bv.y)))));
        o.z = fmaf(w2.z, win2, fmaf(w2.w, win3, fmaf(w3.x, win4, fmaf(w3.y, win5, fmaf(w3.z, win6, bv.z)))));
        o.w = fmaf(w3.w, win3, fmaf(w4.x, win4, fmaf(w4.y, win5, fmaf(w4.z, win6, fmaf(w4.w, win7, bv.w)))));

        orow[chunk] = o;
        xrow += C_CH / 4;
        orow += C_CH / 4;
    }
}

extern "C" void kernel_launch(void* const* d_in, const int* in_sizes, int n_in,
                              void* d_out, int out_size, void* d_ws, size_t ws_size,
                              hipStream_t stream) {
    const float* x    = (const float*)d_in[0];
    const float* W    = (const float*)d_in[1];
    const float* bias = (const float*)d_in[2];
    float* out = (float*)d_out;

    dim3 grid(C_CH / 4 / 256, B_ROWS / ROWS_PER_BLOCK);  // (4, 512) = 2048 blocks
    dim3 block(256);
    grouped_linear_kernel<<<grid, block, 0, stream>>>(x, W, bias, out);
}